// Round 1
// 232.506 us; speedup vs baseline: 1.0129x; 1.0129x over previous
//
#include <hip/hip_runtime.h>
#include <stdint.h>

#define IN_F 1024
#define OUT_F 1024
#define SCALING 0.25f
#define TILE_ROWS 16
#define BLOCK 256

// LoRA rank-4 streaming kernel. Block = 256 threads = 4 waves, 16 rows/tile.
//
// Phase 1 (h = x@A^T): NO LDS staging of x — x has zero reuse, so it is
//   streamed global->register with coalesced float4 loads (1 KB/instr/wave).
//   Lane owns f4-columns {lane + 64k, k=0..3}; A fragments for those columns
//   live in 16 float4 registers (loaded once, L2-hot across all blocks).
//   Wave w handles rows 4w..4w+3, 2-deep row pipeline (next row's 4 loads in
//   flight during current row's FMAs+reduction). Rank-4 partials are reduced
//   with a 6-stage __shfl_xor butterfly (24 DS-fast ops/row, ~144 cyc — far
//   under the ~800 cyc/row HBM floor). Only 256 B of LDS total -> occupancy
//   is VGPR-limited (~3 waves/SIMD), not LDS-limited (was 3 blocks/CU @49KB).
// Phase 2 (out = h@B^T * s): unchanged from R0 winner — B-frag in regs
//   (loaded after the barrier to keep phase-1 VGPR peak down), h broadcast
//   from LDS, fully coalesced float4 stores (4 KB/row per block).
__global__ __launch_bounds__(BLOCK, 3) void lora_tile(
    const float* __restrict__ x, const float* __restrict__ A,
    const float* __restrict__ B, float* __restrict__ out, int nrows) {
  __shared__ float4 hf[TILE_ROWS];  // 256 B: final h per row

  const int t = threadIdx.x;
  const int lane = t & 63;
  const int wave = t >> 6;
  const int row0 = blockIdx.x * TILE_ROWS;
  if (row0 >= nrows) return;

  // A fragments: a[r][k] covers cols 4*(lane+64k) .. +3 of A row r.
  const float4* __restrict__ A4 = (const float4*)A;
  float4 a[4][4];
#pragma unroll
  for (int r = 0; r < 4; ++r)
#pragma unroll
    for (int k = 0; k < 4; ++k) a[r][k] = A4[r * 256 + lane + 64 * k];

  // Phase 1: wave's 4 rows, x straight from global, 2-deep pipeline.
  const float4* __restrict__ x4 =
      (const float4*)(x + (size_t)(row0 + wave * 4) * IN_F);

  float4 xr[2][4];
#pragma unroll
  for (int k = 0; k < 4; ++k) xr[0][k] = x4[lane + 64 * k];

#pragma unroll
  for (int i = 0; i < 4; ++i) {
    if (i + 1 < 4) {
#pragma unroll
      for (int k = 0; k < 4; ++k)
        xr[(i + 1) & 1][k] = x4[(i + 1) * 256 + lane + 64 * k];
    }
    float p0 = 0.f, p1 = 0.f, p2 = 0.f, p3 = 0.f;
#pragma unroll
    for (int k = 0; k < 4; ++k) {
      const float4 xv = xr[i & 1][k];  // static index after unroll
      p0 += xv.x * a[0][k].x + xv.y * a[0][k].y + xv.z * a[0][k].z +
            xv.w * a[0][k].w;
      p1 += xv.x * a[1][k].x + xv.y * a[1][k].y + xv.z * a[1][k].z +
            xv.w * a[1][k].w;
      p2 += xv.x * a[2][k].x + xv.y * a[2][k].y + xv.z * a[2][k].z +
            xv.w * a[2][k].w;
      p3 += xv.x * a[3][k].x + xv.y * a[3][k].y + xv.z * a[3][k].z +
            xv.w * a[3][k].w;
    }
    // 6-stage butterfly across the full wave; every lane ends with the sum.
#pragma unroll
    for (int off = 1; off < 64; off <<= 1) {
      p0 += __shfl_xor(p0, off, 64);
      p1 += __shfl_xor(p1, off, 64);
      p2 += __shfl_xor(p2, off, 64);
      p3 += __shfl_xor(p3, off, 64);
    }
    if (lane == 0)
      hf[wave * 4 + i] = make_float4(p0 * SCALING, p1 * SCALING, p2 * SCALING,
                                     p3 * SCALING);
  }
  __syncthreads();

  // Phase 2: B fragment loaded here (post-barrier) so its 16 VGPRs don't
  // stack on phase 1's peak. Thread t owns out f4-column t for all 16 rows.
  const float4* __restrict__ B4 = (const float4*)B;
  const float4 bf0 = B4[4 * t + 0];
  const float4 bf1 = B4[4 * t + 1];
  const float4 bf2 = B4[4 * t + 2];
  const float4 bf3 = B4[4 * t + 3];

  float4* __restrict__ out4 = (float4*)out;
#pragma unroll
  for (int r = 0; r < TILE_ROWS; ++r) {
    const float4 h = hf[r];  // same addr all lanes -> LDS broadcast
    float4 res;
    res.x = h.x * bf0.x + h.y * bf0.y + h.z * bf0.z + h.w * bf0.w;
    res.y = h.x * bf1.x + h.y * bf1.y + h.z * bf1.z + h.w * bf1.w;
    res.z = h.x * bf2.x + h.y * bf2.y + h.z * bf2.z + h.w * bf2.w;
    res.w = h.x * bf3.x + h.y * bf3.y + h.z * bf3.z + h.w * bf3.w;
    out4[(size_t)(row0 + r) * (OUT_F / 4) + t] = res;
  }
}

extern "C" void kernel_launch(void* const* d_in, const int* in_sizes, int n_in,
                              void* d_out, int out_size, void* d_ws,
                              size_t ws_size, hipStream_t stream) {
  const float* x = (const float*)d_in[0];
  const float* A = (const float*)d_in[1];
  const float* B = (const float*)d_in[2];
  float* out = (float*)d_out;

  const int nrows = in_sizes[0] / IN_F;                    // 32768
  const int blocks = (nrows + TILE_ROWS - 1) / TILE_ROWS;  // 2048
  lora_tile<<<blocks, BLOCK, 0, stream>>>(x, A, B, out, nrows);
}